// Round 1
// baseline (3023.098 us; speedup 1.0000x reference)
//
#include <hip/hip_runtime.h>
#include <cstdint>
#include <cstddef>

// Problem dims
#define B_   64
#define S_   512
#define E_   300
#define EP   320     // E padded to multiple of 32 (zero pad)
#define H_   512
#define G3   1536    // packed gates: [i(512), g(512), o(512)] (f-gate unused: c_prev==0)

typedef float  f32x4 __attribute__((ext_vector_type(4)));
typedef short  s16x8 __attribute__((ext_vector_type(8)));

__device__ __forceinline__ unsigned short f2bf(float f) {
  union { float f; unsigned u; } v; v.f = f;
  return (unsigned short)((v.u + 0x7fffu + ((v.u >> 16) & 1u)) >> 16);  // RNE
}
__device__ __forceinline__ float bf2f(unsigned short s) {
  union { unsigned u; float f; } v; v.u = ((unsigned)s) << 16;
  return v.f;
}
__device__ __forceinline__ float sigm(float x) { return 1.0f / (1.0f + __expf(-x)); }
__device__ __forceinline__ float tanhf_(float x) { return 2.0f / (1.0f + __expf(-2.0f * x)) - 1.0f; }
// h = sigmoid(o) * tanh(sigmoid(i) * tanh(g))   (c_prev == 0, faithful to reference)
__device__ __forceinline__ float cellh(float i, float g, float o) {
  float c = sigm(i) * tanhf_(g);
  return sigm(o) * tanhf_(c);
}

// gate-buffer load/store, fp32 or bf16 tier
__device__ __forceinline__ float ldG(const float* p, long i) { return p[i]; }
__device__ __forceinline__ float ldG(const unsigned short* p, long i) { return bf2f(p[i]); }
__device__ __forceinline__ void stG(float* p, long i, float v) { p[i] = v; }
__device__ __forceinline__ void stG(unsigned short* p, long i, float v) { p[i] = f2bf(v); }
__device__ __forceinline__ void ld2G(const float* p, long i, float& a, float& b) {
  float2 t = *(const float2*)(p + i); a = t.x; b = t.y;
}
__device__ __forceinline__ void ld2G(const unsigned short* p, long i, float& a, float& b) {
  unsigned u = *(const unsigned*)(p + i);
  a = bf2f((unsigned short)(u & 0xffffu)); b = bf2f((unsigned short)(u >> 16));
}

// ---------------------------------------------------------------------------
// prep: pack W_ih_{f,b} rows [i,g,o] -> bf16 [1536][320] (zero-pad K), biases
// packed row j -> source gate row: j<512 ? j : j+512   (skips f-rows 512..1023)
// ---------------------------------------------------------------------------
__global__ __launch_bounds__(256)
void prep_kernel(const float* __restrict__ Wf, const float* __restrict__ Wb,
                 const float* __restrict__ bihf, const float* __restrict__ bhhf,
                 const float* __restrict__ bihb, const float* __restrict__ bhhb,
                 unsigned short* __restrict__ Wfp, unsigned short* __restrict__ Wbp,
                 float* __restrict__ bpf, float* __restrict__ bpb) {
  const int t0 = blockIdx.x * blockDim.x + threadIdx.x;
  const int stride = gridDim.x * blockDim.x;
  const int tot = G3 * EP;
  for (int idx = t0; idx < tot; idx += stride) {
    const int n = idx / EP, k = idx - n * EP;
    const int src = (n < H_) ? n : n + H_;
    const float vf = (k < E_) ? Wf[(size_t)src * E_ + k] : 0.0f;
    const float vb = (k < E_) ? Wb[(size_t)src * E_ + k] : 0.0f;
    Wfp[idx] = f2bf(vf);
    Wbp[idx] = f2bf(vb);
  }
  for (int n = t0; n < G3; n += stride) {
    const int src = (n < H_) ? n : n + H_;
    bpf[n] = bihf[src] + bhhf[src];
    bpb[n] = bihb[src] + bhhb[src];
  }
}

// ---------------------------------------------------------------------------
// xstage: x = embed_table[inputs] -> bf16 [32768][320] (zero-pad cols 300..319)
// ---------------------------------------------------------------------------
__global__ __launch_bounds__(256)
void xstage_kernel(const int* __restrict__ inp, const float* __restrict__ emb,
                   unsigned short* __restrict__ xbf) {
  const int t = blockIdx.x * blockDim.x + threadIdx.x;   // 32768*80 threads
  const int row = t / 80, q = t - row * 80;
  const int c0 = q * 4;
  const int vid = inp[row];
  unsigned short o[4];
#pragma unroll
  for (int e = 0; e < 4; ++e) {
    const int c = c0 + e;
    o[e] = (c < E_) ? f2bf(emb[(size_t)vid * E_ + c]) : (unsigned short)0;
  }
  uint2 pv;
  pv.x = (unsigned)o[0] | ((unsigned)o[1] << 16);
  pv.y = (unsigned)o[2] | ((unsigned)o[3] << 16);
  *(uint2*)&xbf[(size_t)row * EP + c0] = pv;
}

// ---------------------------------------------------------------------------
// GEMM: C[r][n] = sum_k A[r][k]*W[n][k] + bias[n]
// A = xbf [32768][320] bf16, W = packed [1536][320] bf16.
// REMAP: output row r=(b*512+s) stored at s*64+b (layout the scan wants).
// Tile 128x128, BK=32, 4 waves (2x2), 16x16x32 MFMA. Register-staged LDS,
// +8-ushort pad per row so fragment ds_read_b128 is ~2-way (free).
// ---------------------------------------------------------------------------
template<bool REMAP, typename GT>
__global__ __launch_bounds__(256)
void gemm_kernel(const unsigned short* __restrict__ A, const unsigned short* __restrict__ W,
                 const float* __restrict__ bias, GT* __restrict__ C) {
  __shared__ short lA[128 * 40];
  __shared__ short lB[128 * 40];
  const int tid = threadIdx.x;
  const int w = tid >> 6, l = tid & 63;
  const int wr = w >> 1, wc = w & 1;
  const int Mb = blockIdx.x * 128, Nb = blockIdx.y * 128;
  f32x4 acc[4][4];
#pragma unroll
  for (int i = 0; i < 4; ++i)
#pragma unroll
    for (int j = 0; j < 4; ++j) acc[i][j] = f32x4{0.f, 0.f, 0.f, 0.f};

  const int srow = tid >> 1, shalf = (tid & 1) * 16;
  for (int kk = 0; kk < EP; kk += 32) {
    const s16x8* ga = (const s16x8*)&A[(size_t)(Mb + srow) * EP + kk + shalf];
    const s16x8* gb = (const s16x8*)&W[(size_t)(Nb + srow) * EP + kk + shalf];
    s16x8 a0 = ga[0], a1 = ga[1], b0 = gb[0], b1 = gb[1];
    *(s16x8*)&lA[srow * 40 + shalf]     = a0;
    *(s16x8*)&lA[srow * 40 + shalf + 8] = a1;
    *(s16x8*)&lB[srow * 40 + shalf]     = b0;
    *(s16x8*)&lB[srow * 40 + shalf + 8] = b1;
    __syncthreads();
    s16x8 af[4], bf[4];
#pragma unroll
    for (int mt = 0; mt < 4; ++mt)
      af[mt] = *(const s16x8*)&lA[(wr * 64 + mt * 16 + (l & 15)) * 40 + 8 * (l >> 4)];
#pragma unroll
    for (int nt = 0; nt < 4; ++nt)
      bf[nt] = *(const s16x8*)&lB[(wc * 64 + nt * 16 + (l & 15)) * 40 + 8 * (l >> 4)];
#pragma unroll
    for (int mt = 0; mt < 4; ++mt)
#pragma unroll
      for (int nt = 0; nt < 4; ++nt)
        acc[mt][nt] = __builtin_amdgcn_mfma_f32_16x16x32_bf16(af[mt], bf[nt], acc[mt][nt], 0, 0, 0);
    __syncthreads();
  }
  // epilogue: C/D layout col=lane&15, row=(lane>>4)*4+reg  [HW-verified]
#pragma unroll
  for (int mt = 0; mt < 4; ++mt) {
#pragma unroll
    for (int nt = 0; nt < 4; ++nt) {
      const int gc = Nb + wc * 64 + nt * 16 + (l & 15);
      const float bv = bias[gc];
#pragma unroll
      for (int r = 0; r < 4; ++r) {
        const int gr = Mb + wr * 64 + mt * 16 + (l >> 4) * 4 + r;
        const int orow = REMAP ? (((gr & 511) << 6) | (gr >> 9)) : gr;
        stG(C, (long)orow * G3 + gc, acc[mt][nt][r] + bv);
      }
    }
  }
}

// ---------------------------------------------------------------------------
// cellmax: out[b][j] = max_s cell(Gf[b,s,j], Gf[b,s,512+j], Gf[b,s,1024+j])
// one WG per batch element; thread handles j pair (2*tid, 2*tid+1)
// ---------------------------------------------------------------------------
template<typename GT>
__global__ __launch_bounds__(256)
void cellmax_kernel(const GT* __restrict__ G, float* __restrict__ out) {
  const int b = blockIdx.x, tid = threadIdx.x;
  const int j0 = tid * 2;
  float mx0 = -2.f, mx1 = -2.f;
  for (int s = 0; s < S_; ++s) {
    const long base = (long)(b * S_ + s) * G3;
    float i0, i1, g0, g1, o0, o1;
    ld2G(G, base + j0, i0, i1);
    ld2G(G, base + 512 + j0, g0, g1);
    ld2G(G, base + 1024 + j0, o0, o1);
    mx0 = fmaxf(mx0, cellh(i0, g0, o0));
    mx1 = fmaxf(mx1, cellh(i1, g1, o1));
  }
  out[b * 1024 + j0] = mx0;
  out[b * 1024 + j0 + 1] = mx1;
}

__global__ void zero_ctr_kernel(unsigned int* c) { if (threadIdx.x < 64) c[threadIdx.x] = 0; }

// ---------------------------------------------------------------------------
// scan: backward LSTM, 512 sequential steps.
// 64 WGs = 4 groups (16 batch rows each) x 16 WGs (96 gates = j-range of 32).
// Each WG keeps its W_hh slice (96x512 bf16 = 98KB) in LDS, fragment-ordered.
// Per step: 24 MFMA 16x16x32; group exchanges h (16x512 bf16) via agent-scope
// (LLC-coherent) loads/stores + monotone counting barrier. Double-buffered h.
// ---------------------------------------------------------------------------
template<typename GT>
__global__ __launch_bounds__(384)
void scan_kernel(const float* __restrict__ Whh, const GT* __restrict__ Gb,
                 unsigned int* __restrict__ hbuf, unsigned int* __restrict__ ctr,
                 float* __restrict__ out) {
  __shared__ short wlds[6 * 16 * 64 * 8];      // 98304 B: [tile][kc][lane][8]
  __shared__ unsigned int hl[16 * 260];        // 16640 B: h as [16][260] uint (=[16][520] bf16, padded)
  __shared__ float gbuf[6][16][20];            // 7680 B: gate tiles for nonlinearity phase

  const int tid = threadIdx.x;
  const int wv = tid >> 6, l = tid & 63;
  const int grp = blockIdx.x >> 4, w = blockIdx.x & 15;
  const int jbase = w * 32;
  // tile t (0..5): gates n_base = (t>>1)*512 + (t&1)*16 + jbase   (i,i,g,g,o,o)

  // one-time: W_hh slice -> LDS, fragment order (lane n = ln&15, k = kc*32+8*(ln>>4)+e)
  for (int u = tid; u < 6144; u += 384) {
    const int tile = u >> 10, rem = u & 1023;
    const int kc = rem >> 6, ln = rem & 63;
    const int n = (tile >> 1) * 512 + (tile & 1) * 16 + jbase + (ln & 15);
    const int src = (n < 512) ? n : n + 512;     // packed igo -> original gate row
    const int k = kc * 32 + 8 * (ln >> 4);
    const float4* sp = (const float4*)&Whh[(size_t)src * 512 + k];
    float4 v0 = sp[0], v1 = sp[1];
    s16x8 vv;
    vv[0] = (short)f2bf(v0.x); vv[1] = (short)f2bf(v0.y);
    vv[2] = (short)f2bf(v0.z); vv[3] = (short)f2bf(v0.w);
    vv[4] = (short)f2bf(v1.x); vv[5] = (short)f2bf(v1.y);
    vv[6] = (short)f2bf(v1.z); vv[7] = (short)f2bf(v1.w);
    *(s16x8*)&wlds[u * 8] = vv;
  }
  __syncthreads();

  const int myn = (wv >> 1) * 512 + (wv & 1) * 16 + jbase;
  const int mrow = (l >> 4) * 4;                     // C/D row base
  const int hm = tid >> 4, hj = (tid & 15) * 2;      // h-phase coords (tid<256)
  float mx0 = -2.f, mx1 = -2.f;
  const unsigned short* hls = (const unsigned short*)hl;

  for (int t = S_ - 1; t >= 0; --t) {
    // prefetch x-gates for this step (independent of barrier -> hides HBM latency)
    float xg[4];
    {
      const long rbase = (long)(t * 64 + grp * 16 + mrow) * G3 + (myn + (l & 15));
#pragma unroll
      for (int r = 0; r < 4; ++r) xg[r] = ldG(Gb, rbase + (long)r * G3);
    }
    if (t != S_ - 1) {
      if (tid == 0) {
        const unsigned target = (unsigned)(S_ - 1 - t) * 16u;
        for (int it = 0; it < (1 << 22); ++it) {   // bounded spin: deadlock -> garbage, not hang
          if (__hip_atomic_load(&ctr[grp], __ATOMIC_ACQUIRE, __HIP_MEMORY_SCOPE_AGENT) >= target)
            break;
        }
      }
      __syncthreads();
      // stage group h (written at step t+1, parity (t+1)&1) -> LDS
      const unsigned long long* hsrc =
          (const unsigned long long*)&hbuf[(((t + 1) & 1) * 4 + grp) * 4096];
      for (int idx = tid; idx < 2048; idx += 384) {
        unsigned long long v = __hip_atomic_load(&hsrc[idx], __ATOMIC_RELAXED, __HIP_MEMORY_SCOPE_AGENT);
        *(unsigned long long*)&hl[(idx >> 7) * 260 + (idx & 127) * 2] = v;
      }
      __syncthreads();
    }
    // gates = h @ Whh_slice^T  (4 independent MFMA chains), + x-gates
    f32x4 a0 = {0,0,0,0}, a1 = {0,0,0,0}, a2 = {0,0,0,0}, a3 = {0,0,0,0};
    if (t != S_ - 1) {
#pragma unroll
      for (int kc = 0; kc < 16; kc += 4) {
        s16x8 fa, fb;
        fa = *(const s16x8*)&hls[(l & 15) * 520 + (kc + 0) * 32 + 8 * (l >> 4)];
        fb = *(const s16x8*)&wlds[((wv * 16 + kc + 0) * 64 + l) * 8];
        a0 = __builtin_amdgcn_mfma_f32_16x16x32_bf16(fa, fb, a0, 0, 0, 0);
        fa = *(const s16x8*)&hls[(l & 15) * 520 + (kc + 1) * 32 + 8 * (l >> 4)];
        fb = *(const s16x8*)&wlds[((wv * 16 + kc + 1) * 64 + l) * 8];
        a1 = __builtin_amdgcn_mfma_f32_16x16x32_bf16(fa, fb, a1, 0, 0, 0);
        fa = *(const s16x8*)&hls[(l & 15) * 520 + (kc + 2) * 32 + 8 * (l >> 4)];
        fb = *(const s16x8*)&wlds[((wv * 16 + kc + 2) * 64 + l) * 8];
        a2 = __builtin_amdgcn_mfma_f32_16x16x32_bf16(fa, fb, a2, 0, 0, 0);
        fa = *(const s16x8*)&hls[(l & 15) * 520 + (kc + 3) * 32 + 8 * (l >> 4)];
        fb = *(const s16x8*)&wlds[((wv * 16 + kc + 3) * 64 + l) * 8];
        a3 = __builtin_amdgcn_mfma_f32_16x16x32_bf16(fa, fb, a3, 0, 0, 0);
      }
    }
#pragma unroll
    for (int r = 0; r < 4; ++r)
      gbuf[wv][mrow + r][l & 15] = ((a0[r] + a1[r]) + (a2[r] + a3[r])) + xg[r];
    __syncthreads();
    // nonlinearity + max + publish h (threads 0..255 own (m, j-pair))
    if (tid < 256) {
      const int tb0 = hj >> 4, c0 = hj & 15;
      const int hj1 = hj + 1, tb1 = hj1 >> 4, c1 = hj1 & 15;
      const float h0 = cellh(gbuf[tb0][hm][c0], gbuf[2 + tb0][hm][c0], gbuf[4 + tb0][hm][c0]);
      const float h1 = cellh(gbuf[tb1][hm][c1], gbuf[2 + tb1][hm][c1], gbuf[4 + tb1][hm][c1]);
      mx0 = fmaxf(mx0, h0);
      mx1 = fmaxf(mx1, h1);
      const unsigned pk = (unsigned)f2bf(h0) | ((unsigned)f2bf(h1) << 16);
      unsigned* dst = &hbuf[((t & 1) * 4 + grp) * 4096 + hm * 256 + ((jbase + hj) >> 1)];
      __hip_atomic_store(dst, pk, __ATOMIC_RELAXED, __HIP_MEMORY_SCOPE_AGENT);
    }
    __syncthreads();
    if (tid == 0)
      __hip_atomic_fetch_add(&ctr[grp], 1u, __ATOMIC_RELEASE, __HIP_MEMORY_SCOPE_AGENT);
  }
  if (tid < 256) {
    const int b = grp * 16 + hm;
    out[b * 1024 + 512 + jbase + hj]     = mx0;
    out[b * 1024 + 512 + jbase + hj + 1] = mx1;
  }
}

// ---------------------------------------------------------------------------
extern "C" void kernel_launch(void* const* d_in, const int* in_sizes, int n_in,
                              void* d_out, int out_size, void* d_ws, size_t ws_size,
                              hipStream_t stream) {
  const int*   inp  = (const int*)  d_in[0];
  const float* emb  = (const float*)d_in[1];
  const float* Wihf = (const float*)d_in[2];
  // d_in[3] = W_hh_f: unused (forward state is always zero)
  const float* bihf = (const float*)d_in[4];
  const float* bhhf = (const float*)d_in[5];
  const float* Wihb = (const float*)d_in[6];
  const float* Whhb = (const float*)d_in[7];
  const float* bihb = (const float*)d_in[8];
  const float* bhhb = (const float*)d_in[9];
  float* out = (float*)d_out;
  char* ws = (char*)d_ws;

  const size_t o_xbf  = 0;                       // 32768*320*2  = 20971520
  const size_t o_Wfp  = o_xbf + 20971520;        // 1536*320*2   = 983040
  const size_t o_Wbp  = o_Wfp + 983040;
  const size_t o_bpf  = o_Wbp + 983040;          // 1536*4
  const size_t o_bpb  = o_bpf + 6144;
  const size_t o_hbuf = o_bpb + 6144;            // 2*4*16*256*4 = 131072
  const size_t o_ctr  = o_hbuf + 131072;         // 256
  const size_t o_G    = o_ctr + 256;
  const size_t need_f32 = o_G + (size_t)32768 * G3 * 4;   // ~214 MB

  unsigned short* xbf = (unsigned short*)(ws + o_xbf);
  unsigned short* Wfp = (unsigned short*)(ws + o_Wfp);
  unsigned short* Wbp = (unsigned short*)(ws + o_Wbp);
  float* bpf = (float*)(ws + o_bpf);
  float* bpb = (float*)(ws + o_bpb);
  unsigned int* hbuf = (unsigned int*)(ws + o_hbuf);
  unsigned int* ctr  = (unsigned int*)(ws + o_ctr);
  void* G = (void*)(ws + o_G);

  hipLaunchKernelGGL(prep_kernel, dim3(512), dim3(256), 0, stream,
                     Wihf, Wihb, bihf, bhhf, bihb, bhhb, Wfp, Wbp, bpf, bpb);
  hipLaunchKernelGGL(xstage_kernel, dim3(10240), dim3(256), 0, stream, inp, emb, xbf);
  hipLaunchKernelGGL(zero_ctr_kernel, dim3(1), dim3(64), 0, stream, ctr);

  if (ws_size >= need_f32) {
    float* Gbuf = (float*)G;
    hipLaunchKernelGGL((gemm_kernel<false, float>), dim3(256, 12), dim3(256), 0, stream,
                       xbf, Wfp, bpf, Gbuf);
    hipLaunchKernelGGL((cellmax_kernel<float>), dim3(64), dim3(256), 0, stream, Gbuf, out);
    hipLaunchKernelGGL((gemm_kernel<true, float>), dim3(256, 12), dim3(256), 0, stream,
                       xbf, Wbp, bpb, Gbuf);
    hipLaunchKernelGGL((scan_kernel<float>), dim3(64), dim3(384), 0, stream,
                       Whhb, Gbuf, hbuf, ctr, out);
  } else {
    // fallback tier: bf16 gate buffer (~113 MB total ws)
    unsigned short* Gbuf = (unsigned short*)G;
    hipLaunchKernelGGL((gemm_kernel<false, unsigned short>), dim3(256, 12), dim3(256), 0, stream,
                       xbf, Wfp, bpf, Gbuf);
    hipLaunchKernelGGL((cellmax_kernel<unsigned short>), dim3(64), dim3(256), 0, stream, Gbuf, out);
    hipLaunchKernelGGL((gemm_kernel<true, unsigned short>), dim3(256, 12), dim3(256), 0, stream,
                       xbf, Wbp, bpb, Gbuf);
    hipLaunchKernelGGL((scan_kernel<unsigned short>), dim3(64), dim3(384), 0, stream,
                       Whhb, Gbuf, hbuf, ctr, out);
  }
}